// Round 1
// baseline (85.588 us; speedup 1.0000x reference)
//
#include <hip/hip_runtime.h>

// Problem constants (from reference): B=1024, D=512, K=256, NC=1.
// out[b,k] = sum_d (x[b,d]-m[k,d])^2 * 0.5*softplus(rho[k,d])^2
// Expanded: out[b,k] = sum_d x*(w*x + a2) + c[k],  w=0.5*sp^2, a2=-2*w*m, c=sum w*m^2

#define BB 1024
#define DD 512
#define KK 256
#define SS 4              // split-K slices over D
#define DSL (DD / SS)     // 128 d per slice
#define BT 64             // batch tile
#define KT 64             // class tile
#define DC 32             // d chunk staged in LDS
#define LSTR 68           // LDS row stride (floats): 16B aligned, bank-swizzled

__global__ __launch_bounds__(256) void prep_kernel(const float* __restrict__ means,
                                                   const float* __restrict__ rho,
                                                   float* __restrict__ w,
                                                   float* __restrict__ a2,
                                                   float* __restrict__ c) {
    const int k = blockIdx.x;           // one block per class k
    const int t = threadIdx.x;
    __shared__ float red[256];
    float csum = 0.f;
    for (int d = t; d < DD; d += 256) {
        const float r  = rho[k * DD + d];
        const float m  = means[k * DD + d];
        const float sp = log1pf(expf(r));       // softplus, rho in [-0.05,0.05] -> safe
        const float wv = 0.5f * sp * sp;
        w[k * DD + d]  = wv;
        a2[k * DD + d] = -2.0f * wv * m;
        csum += wv * m * m;
    }
    red[t] = csum;
    __syncthreads();
    for (int off = 128; off > 0; off >>= 1) {
        if (t < off) red[t] += red[t + off];
        __syncthreads();
    }
    if (t == 0) c[k] = red[0];
}

__global__ __launch_bounds__(256) void main_kernel(const float* __restrict__ x,
                                                   const float* __restrict__ w,
                                                   const float* __restrict__ a2,
                                                   const float* __restrict__ c,
                                                   float* __restrict__ out) {
    __shared__ float xT[DC][LSTR];   // [d][b_local]
    __shared__ float wT[DC][LSTR];   // [d][k_local]
    __shared__ float aT[DC][LSTR];   // [d][k_local]

    const int t  = threadIdx.x;
    const int tx = t & 15;           // k micro index
    const int ty = t >> 4;           // b micro index
    const int k0 = blockIdx.x * KT;
    const int b0 = blockIdx.y * BT;
    const int d0 = blockIdx.z * DSL;

    const int lr  = t >> 3;          // 0..31: row group for staging
    const int ld4 = (t & 7) * 4;     // 0,4,..,28: d offset for staging

    float acc[4][4];
#pragma unroll
    for (int i = 0; i < 4; i++)
#pragma unroll
        for (int j = 0; j < 4; j++) acc[i][j] = 0.f;

    for (int dcBase = 0; dcBase < DSL; dcBase += DC) {
        const int dg = d0 + dcBase + ld4;  // global d of this thread's float4
        // stage x: rows b0..b0+63 (two halves of 32), cols dg..dg+3, transposed
#pragma unroll
        for (int half = 0; half < 2; half++) {
            const int row = lr + half * 32;
            const float4 xv = *(const float4*)&x[(b0 + row) * DD + dg];
            xT[ld4 + 0][row] = xv.x;
            xT[ld4 + 1][row] = xv.y;
            xT[ld4 + 2][row] = xv.z;
            xT[ld4 + 3][row] = xv.w;
            const float4 wv = *(const float4*)&w[(k0 + row) * DD + dg];
            wT[ld4 + 0][row] = wv.x;
            wT[ld4 + 1][row] = wv.y;
            wT[ld4 + 2][row] = wv.z;
            wT[ld4 + 3][row] = wv.w;
            const float4 av = *(const float4*)&a2[(k0 + row) * DD + dg];
            aT[ld4 + 0][row] = av.x;
            aT[ld4 + 1][row] = av.y;
            aT[ld4 + 2][row] = av.z;
            aT[ld4 + 3][row] = av.w;
        }
        __syncthreads();

#pragma unroll
        for (int d = 0; d < DC; d++) {
            const float4 xv = *(const float4*)&xT[d][ty * 4];
            const float4 wv = *(const float4*)&wT[d][tx * 4];
            const float4 av = *(const float4*)&aT[d][tx * 4];
            const float xs[4] = {xv.x, xv.y, xv.z, xv.w};
            const float ws[4] = {wv.x, wv.y, wv.z, wv.w};
            const float as[4] = {av.x, av.y, av.z, av.w};
#pragma unroll
            for (int i = 0; i < 4; i++)
#pragma unroll
                for (int j = 0; j < 4; j++) {
                    const float tmp = fmaf(ws[j], xs[i], as[j]);
                    acc[i][j] = fmaf(tmp, xs[i], acc[i][j]);
                }
        }
        __syncthreads();
    }

    // fold bias c[k] in exactly once (slice 0), then atomically accumulate
    float cv[4] = {0.f, 0.f, 0.f, 0.f};
    if (blockIdx.z == 0) {
#pragma unroll
        for (int j = 0; j < 4; j++) cv[j] = c[k0 + tx * 4 + j];
    }
#pragma unroll
    for (int i = 0; i < 4; i++) {
        const int b = b0 + ty * 4 + i;
#pragma unroll
        for (int j = 0; j < 4; j++) {
            const int k = k0 + tx * 4 + j;
            atomicAdd(&out[b * KK + k], acc[i][j] + cv[j]);
        }
    }
}

extern "C" void kernel_launch(void* const* d_in, const int* in_sizes, int n_in,
                              void* d_out, int out_size, void* d_ws, size_t ws_size,
                              hipStream_t stream) {
    const float* x     = (const float*)d_in[0];
    const float* means = (const float*)d_in[1];
    const float* rho   = (const float*)d_in[2];
    float* out = (float*)d_out;

    float* w  = (float*)d_ws;                 // K*D floats = 512 KB
    float* a2 = w + KK * DD;                  // K*D floats = 512 KB
    float* c  = a2 + KK * DD;                 // K floats

    // out accumulated via atomics -> must start at zero every call
    hipMemsetAsync(d_out, 0, (size_t)out_size * sizeof(float), stream);

    prep_kernel<<<KK, 256, 0, stream>>>(means, rho, w, a2, c);

    dim3 grid(KK / KT, BB / BT, SS);
    main_kernel<<<grid, 256, 0, stream>>>(x, w, a2, c, out);
}

// Round 2
// 71.248 us; speedup vs baseline: 1.2013x; 1.2013x over previous
//
#include <hip/hip_runtime.h>
#include <hip/hip_bf16.h>

// Problem: B=1024, D=512, K=256, NC=1.
// out[b,k] = sum_d (x[b,d]-m[k,d])^2 * 0.5*softplus(rho[k,d])^2
//          = sum_d w*x^2 + a2*x  + c[k],   w=0.5*sp^2, a2=-2*w*m, c=sum w*m^2
// => GEMM: out = X' * W'^T + c,  X'=[x^2, x] (B x 1024 bf16), W'=[w, a2] (K x 1024 bf16)

#define BB 1024
#define DD 512
#define DP 1024          // D' = 2*D
#define KK 256

typedef __attribute__((ext_vector_type(8))) short bf16x8;
typedef __attribute__((ext_vector_type(4))) float f32x4;
typedef __attribute__((ext_vector_type(4))) unsigned short us4;

static __device__ inline unsigned short f2bf(float f) {
    __hip_bfloat16 h = __float2bfloat16(f);   // round-to-nearest-even
    return *reinterpret_cast<unsigned short*>(&h);
}

// X'[b, d] = bf16(x^2), X'[b, 512+d] = bf16(x). 4 elems per thread.
__global__ __launch_bounds__(256) void prep_x_kernel(const float* __restrict__ x,
                                                     unsigned short* __restrict__ Xp) {
    const int i = blockIdx.x * 256 + threadIdx.x;   // 131072 threads, 4 d each
    const int b = i >> 7;            // 512/4 = 128 groups per row
    const int d4 = (i & 127) * 4;
    const float4 xv = *(const float4*)&x[b * DD + d4];
    us4 sq, ln;
    sq.x = f2bf(xv.x * xv.x); sq.y = f2bf(xv.y * xv.y);
    sq.z = f2bf(xv.z * xv.z); sq.w = f2bf(xv.w * xv.w);
    ln.x = f2bf(xv.x); ln.y = f2bf(xv.y); ln.z = f2bf(xv.z); ln.w = f2bf(xv.w);
    *(us4*)&Xp[b * DP + d4]      = sq;
    *(us4*)&Xp[b * DP + DD + d4] = ln;
}

// W'[k, d] = bf16(w), W'[k, 512+d] = bf16(a2), c[k] = sum_d w*m^2 (fp32)
__global__ __launch_bounds__(256) void prep_w_kernel(const float* __restrict__ means,
                                                     const float* __restrict__ rho,
                                                     unsigned short* __restrict__ Wp,
                                                     float* __restrict__ c) {
    const int k = blockIdx.x;
    const int t = threadIdx.x;
    __shared__ float red[256];
    float csum = 0.f;
#pragma unroll
    for (int d = t; d < DD; d += 256) {
        const float r  = rho[k * DD + d];
        const float m  = means[k * DD + d];
        const float sp = log1pf(expf(r));
        const float wv = 0.5f * sp * sp;
        Wp[k * DP + d]      = f2bf(wv);
        Wp[k * DP + DD + d] = f2bf(-2.0f * wv * m);
        csum += wv * m * m;
    }
    red[t] = csum;
    __syncthreads();
    for (int off = 128; off > 0; off >>= 1) {
        if (t < off) red[t] += red[t + off];
        __syncthreads();
    }
    if (t == 0) c[k] = red[0];
}

// One 16x16 out-tile per wave, K-loop over D'=1024 in steps of 32.
// 1024 wave-tiles = 256 blocks x 4 waves.
__global__ __launch_bounds__(256) void gemm_kernel(const unsigned short* __restrict__ Xp,
                                                   const unsigned short* __restrict__ Wp,
                                                   const float* __restrict__ c,
                                                   float* __restrict__ out) {
    const int lane = threadIdx.x & 63;
    const int wave = threadIdx.x >> 6;
    const int tile = blockIdx.x * 4 + wave;       // 0..1023
    const int kb = tile & 15;                     // 16 k-tiles
    const int bb = tile >> 4;                     // 64 b-tiles
    const int k0 = kb * 16;
    const int b0 = bb * 16;

    const int rc   = lane & 15;       // A: row(m)=b index; B: col(n)=k index
    const int quad = lane >> 4;       // k-offset group (8 bf16 each)

    const unsigned short* aRow = Xp + (b0 + rc) * DP + quad * 8;
    const unsigned short* bRow = Wp + (k0 + rc) * DP + quad * 8;

    f32x4 acc = {0.f, 0.f, 0.f, 0.f};
#pragma unroll 4
    for (int dk = 0; dk < DP; dk += 32) {
        const bf16x8 a = *(const bf16x8*)(aRow + dk);
        const bf16x8 b = *(const bf16x8*)(bRow + dk);
        acc = __builtin_amdgcn_mfma_f32_16x16x32_bf16(a, b, acc, 0, 0, 0);
    }

    // C/D layout: col = lane&15 (n/k), row = (lane>>4)*4 + reg (m/b)
    const int col = rc;
    const int row0 = quad * 4;
    const float cv = c[k0 + col];
#pragma unroll
    for (int r = 0; r < 4; r++) {
        out[(b0 + row0 + r) * KK + (k0 + col)] = acc[r] + cv;
    }
}

extern "C" void kernel_launch(void* const* d_in, const int* in_sizes, int n_in,
                              void* d_out, int out_size, void* d_ws, size_t ws_size,
                              hipStream_t stream) {
    const float* x     = (const float*)d_in[0];
    const float* means = (const float*)d_in[1];
    const float* rho   = (const float*)d_in[2];
    float* out = (float*)d_out;

    unsigned short* Xp = (unsigned short*)d_ws;            // 1024*1024*2 = 2 MB
    unsigned short* Wp = Xp + (size_t)BB * DP;             // 256*1024*2 = 512 KB
    float* c = (float*)(Wp + (size_t)KK * DP);             // 256 floats

    prep_x_kernel<<<(BB * DD / 4) / 256, 256, 0, stream>>>(x, Xp);
    prep_w_kernel<<<KK, 256, 0, stream>>>(means, rho, Wp, c);
    gemm_kernel<<<256, 256, 0, stream>>>(Xp, Wp, c, out);
}